// Round 1
// baseline (181.382 us; speedup 1.0000x reference)
//
#include <hip/hip_runtime.h>

#define GRID_H 20
#define GRID_W 80
#define NCH 264
#define K 256
#define NPIX 128   // 16x8 glyph pixels

typedef __attribute__((ext_vector_type(8))) short short8;
typedef __attribute__((ext_vector_type(4))) float f32x4;
typedef __attribute__((ext_vector_type(8))) unsigned short u16x8;

static __device__ __forceinline__ unsigned short f2bf(float f) {
    unsigned int u = __builtin_bit_cast(unsigned int, f);
    u += 0x7FFFu + ((u >> 16) & 1u);   // round-to-nearest-even
    return (unsigned short)(u >> 16);
}

__global__ __launch_bounds__(320) void ansi_kernel(
        const float* __restrict__ data,
        const float* __restrict__ cm,
        float* __restrict__ out) {
    __shared__ unsigned short Bl[NPIX * K];   // 64 KB, swizzled [p][c]
    __shared__ float fgbg[GRID_W * 8];        // per cell: bg.rgb, diff.rgb, pad2

    const int blk = blockIdx.x;
    const int b = blk / GRID_H;
    const int h = blk % GRID_H;
    const float* dbase = data + (size_t)(b * GRID_H + h) * GRID_W * NCH;
    const int t = threadIdx.x;

    // ---- stage char_matrix into LDS as bf16, transposed [p][c], XOR-swizzled ----
    for (int i = t; i < NPIX * (K / 8); i += 320) {
        int p  = i & (NPIX - 1);
        int cg = i >> 7;                 // channel group of 8
        const float* src = cm + (size_t)cg * 8 * NPIX + p;
        u16x8 pk;
        #pragma unroll
        for (int j = 0; j < 8; ++j) pk[j] = f2bf(src[j * NPIX]);
        int ba = (p * 512 + cg * 16) ^ ((p & 7) << 4);
        *reinterpret_cast<u16x8*>(reinterpret_cast<char*>(Bl) + ba) = pk;
    }

    // ---- stage per-cell fg/bg -> (bg, fg-bg) ----
    for (int w = t; w < GRID_W; w += 320) {
        const float* q = dbase + (size_t)w * NCH + 256;
        float4 a = *reinterpret_cast<const float4*>(q);      // fg_bold, fg.rgb
        float4 c = *reinterpret_cast<const float4*>(q + 4);  // bg_bold, bg.rgb
        float fs = 0.5f * a.x + 0.5f;
        float bs = 0.5f * c.x + 0.5f;
        float bgr = bs * c.y, bgg = bs * c.z, bgb = bs * c.w;
        float* o = &fgbg[w * 8];
        o[0] = bgr; o[1] = bgg; o[2] = bgb;
        o[3] = fs * a.y - bgr; o[4] = fs * a.z - bgg; o[5] = fs * a.w - bgb;
    }

    __syncthreads();

    // ---- main GEMM: wave w handles cells [w*16, w*16+16), all 128 pixels ----
    const int wave = t >> 6;
    const int lane = t & 63;
    const int mrow = lane & 15;     // A row / B col within tile
    const int g    = lane >> 4;     // k-group
    const int cell0 = wave * 16;

    const float* arow = dbase + (size_t)(cell0 + mrow) * NCH + g * 8;

    f32x4 acc[8];
    #pragma unroll
    for (int n = 0; n < 8; ++n) acc[n] = (f32x4){0.f, 0.f, 0.f, 0.f};

    for (int ks = 0; ks < 8; ++ks) {
        float4 a0 = *reinterpret_cast<const float4*>(arow + ks * 32);
        float4 a1 = *reinterpret_cast<const float4*>(arow + ks * 32 + 4);
        u16x8 ap;
        ap[0] = f2bf(a0.x); ap[1] = f2bf(a0.y); ap[2] = f2bf(a0.z); ap[3] = f2bf(a0.w);
        ap[4] = f2bf(a1.x); ap[5] = f2bf(a1.y); ap[6] = f2bf(a1.z); ap[7] = f2bf(a1.w);
        short8 afrag = __builtin_bit_cast(short8, ap);
        const int kbase = ks * 32 + g * 8;
        #pragma unroll
        for (int n = 0; n < 8; ++n) {
            int p = n * 16 + mrow;
            int ba = (p * 512 + kbase * 2) ^ ((p & 7) << 4);
            short8 bfrag = *reinterpret_cast<short8*>(reinterpret_cast<char*>(Bl) + ba);
            acc[n] = __builtin_amdgcn_mfma_f32_16x16x32_bf16(afrag, bfrag, acc[n], 0, 0, 0);
        }
    }

    // ---- epilogue: out = bg + raw * (fg - bg), 3 channels ----
    const int col = lane & 15;
    const int rowbase = (lane >> 4) << 2;

    float bgv[4][3], dv[4][3];
    #pragma unroll
    for (int r = 0; r < 4; ++r) {
        const float* fb = &fgbg[(cell0 + rowbase + r) * 8];
        bgv[r][0] = fb[0]; bgv[r][1] = fb[1]; bgv[r][2] = fb[2];
        dv[r][0]  = fb[3]; dv[r][1]  = fb[4]; dv[r][2]  = fb[5];
    }

    const size_t outbase = ((size_t)b * 320 + h * 16) * 640 * 3;
    #pragma unroll
    for (int n = 0; n < 8; ++n) {
        int p = n * 16 + col;
        int y = p >> 3, x = p & 7;
        #pragma unroll
        for (int r = 0; r < 4; ++r) {
            int cell = cell0 + rowbase + r;
            float raw = acc[n][r];
            size_t idx = outbase + ((size_t)y * 640 + cell * 8 + x) * 3;
            out[idx + 0] = bgv[r][0] + raw * dv[r][0];
            out[idx + 1] = bgv[r][1] + raw * dv[r][1];
            out[idx + 2] = bgv[r][2] + raw * dv[r][2];
        }
    }
}

extern "C" void kernel_launch(void* const* d_in, const int* in_sizes, int n_in,
                              void* d_out, int out_size, void* d_ws, size_t ws_size,
                              hipStream_t stream) {
    (void)in_sizes; (void)n_in; (void)d_ws; (void)ws_size; (void)out_size;
    const float* data = (const float*)d_in[0];
    const float* cm   = (const float*)d_in[1];
    float* out        = (float*)d_out;
    const int nblocks = 128 * GRID_H;   // one block per (b, h)
    ansi_kernel<<<nblocks, 320, 0, stream>>>(data, cm, out);
}

// Round 4
// 160.810 us; speedup vs baseline: 1.1279x; 1.1279x over previous
//
#include <hip/hip_runtime.h>

#define GRID_H 20
#define GRID_W 80
#define NCH 264
#define K 256
#define NPIX 128   // 16x8 glyph pixels

typedef __attribute__((ext_vector_type(8))) short short8;
typedef __attribute__((ext_vector_type(4))) float f32x4;
typedef __attribute__((ext_vector_type(8))) unsigned short u16x8;

static __device__ __forceinline__ unsigned short f2bf(float f) {
    unsigned int u = __builtin_bit_cast(unsigned int, f);
    u += 0x7FFFu + ((u >> 16) & 1u);   // round-to-nearest-even
    return (unsigned short)(u >> 16);
}

__global__ __launch_bounds__(320) void ansi_kernel(
        const float* __restrict__ data,
        const float* __restrict__ cm,
        float* __restrict__ out) {
    // 64 KB B tile, swizzled [p][c] — EXACT R1 layout; reused as output staging
    __shared__ alignas(16) unsigned short Bl[NPIX * K];
    __shared__ float fgbg[GRID_W * 8];   // per cell: bg.rgb, (fg-bg).rgb

    const int blk = blockIdx.x;
    const int b = blk / GRID_H;
    const int h = blk % GRID_H;
    const float* dbase = data + (size_t)(b * GRID_H + h) * GRID_W * NCH;
    const int t = threadIdx.x;

    // ---- stage char_matrix into LDS as bf16, transposed [p][c], XOR-swizzled ----
    for (int i = t; i < NPIX * (K / 8); i += 320) {
        int p  = i & (NPIX - 1);
        int cg = i >> 7;                 // channel group of 8 (0..31)
        const float* src = cm + (size_t)cg * 8 * NPIX + p;
        u16x8 pk;
        #pragma unroll
        for (int j = 0; j < 8; ++j) pk[j] = f2bf(src[j * NPIX]);
        int ba = (p * 512 + cg * 16) ^ ((p & 7) << 4);
        *reinterpret_cast<u16x8*>(reinterpret_cast<char*>(Bl) + ba) = pk;
    }

    // ---- stage per-cell fg/bg -> (bg, fg-bg) ----
    for (int w = t; w < GRID_W; w += 320) {
        const float* q = dbase + (size_t)w * NCH + 256;
        float4 a = *reinterpret_cast<const float4*>(q);      // fg_bold, fg.rgb
        float4 c = *reinterpret_cast<const float4*>(q + 4);  // bg_bold, bg.rgb
        float fs = 0.5f * a.x + 0.5f;
        float bs = 0.5f * c.x + 0.5f;
        float bgr = bs * c.y, bgg = bs * c.z, bgb = bs * c.w;
        float* o = &fgbg[w * 8];
        o[0] = bgr; o[1] = bgg; o[2] = bgb;
        o[3] = fs * a.y - bgr; o[4] = fs * a.z - bgg; o[5] = fs * a.w - bgb;
    }

    __syncthreads();

    // ---- main GEMM (EXACT R1): wave w -> cells [w*16, w*16+16), 128 pixels ----
    const int wave = t >> 6;
    const int lane = t & 63;
    const int mrow = lane & 15;     // A row / B col within tile
    const int g    = lane >> 4;     // k-group
    const int cell0 = wave * 16;

    const float* arow = dbase + (size_t)(cell0 + mrow) * NCH + g * 8;

    f32x4 acc[8];
    #pragma unroll
    for (int n = 0; n < 8; ++n) acc[n] = (f32x4){0.f, 0.f, 0.f, 0.f};

    for (int ks = 0; ks < 8; ++ks) {
        float4 a0 = *reinterpret_cast<const float4*>(arow + ks * 32);
        float4 a1 = *reinterpret_cast<const float4*>(arow + ks * 32 + 4);
        u16x8 ap;
        ap[0] = f2bf(a0.x); ap[1] = f2bf(a0.y); ap[2] = f2bf(a0.z); ap[3] = f2bf(a0.w);
        ap[4] = f2bf(a1.x); ap[5] = f2bf(a1.y); ap[6] = f2bf(a1.z); ap[7] = f2bf(a1.w);
        short8 afrag = __builtin_bit_cast(short8, ap);
        const int kbase = ks * 32 + g * 8;
        #pragma unroll
        for (int n = 0; n < 8; ++n) {
            int p = n * 16 + mrow;
            int ba = (p * 512 + kbase * 2) ^ ((p & 7) << 4);
            short8 bfrag = *reinterpret_cast<short8*>(reinterpret_cast<char*>(Bl) + ba);
            acc[n] = __builtin_amdgcn_mfma_f32_16x16x32_bf16(afrag, bfrag, acc[n], 0, 0, 0);
        }
    }

    __syncthreads();   // NEW: all waves done reading Bl before reuse as staging

    // ---- epilogue: out = bg + raw*(fg-bg), staged via LDS, coalesced stores ----
    const int col = lane & 15;
    const int rowbase = (lane >> 4) << 2;

    float bgv[4][3], dv[4][3];
    #pragma unroll
    for (int r = 0; r < 4; ++r) {
        const float* fb = &fgbg[(cell0 + rowbase + r) * 8];
        bgv[r][0] = fb[0]; bgv[r][1] = fb[1]; bgv[r][2] = fb[2];
        dv[r][0]  = fb[3]; dv[r][1]  = fb[4]; dv[r][2]  = fb[5];
    }

    float* S = (float*)Bl;   // 4 y-lines: 4*640*3 floats = 30720B < 64KB
    const size_t blockbase = ((size_t)b * 320 + h * 16) * 640 * 3;

    #pragma unroll
    for (int pass = 0; pass < 4; ++pass) {
        #pragma unroll
        for (int dn = 0; dn < 2; ++dn) {
            int n = pass * 2 + dn;              // static under unroll
            int pix = n * 16 + col;
            int yy = dn * 2 + (col >> 3);       // y-line within staging buffer
            int x = pix & 7;
            #pragma unroll
            for (int r = 0; r < 4; ++r) {
                int cell = cell0 + rowbase + r;
                float raw = acc[n][r];
                float* o = &S[(yy * 640 + cell * 8 + x) * 3];
                o[0] = bgv[r][0] + raw * dv[r][0];
                o[1] = bgv[r][1] + raw * dv[r][1];
                o[2] = bgv[r][2] + raw * dv[r][2];
            }
        }
        __syncthreads();
        // 7680 floats = 1920 float4 = 6 per thread, fully coalesced
        float4* od = (float4*)(out + blockbase + (size_t)pass * 7680);
        const float4* Sv = (const float4*)S;
        #pragma unroll
        for (int q = 0; q < 6; ++q) {
            int j = q * 320 + t;
            od[j] = Sv[j];
        }
        __syncthreads();   // before next pass overwrites S
    }
}

extern "C" void kernel_launch(void* const* d_in, const int* in_sizes, int n_in,
                              void* d_out, int out_size, void* d_ws, size_t ws_size,
                              hipStream_t stream) {
    (void)in_sizes; (void)n_in; (void)d_ws; (void)ws_size; (void)out_size;
    const float* data = (const float*)d_in[0];
    const float* cm   = (const float*)d_in[1];
    float* out        = (float*)d_out;
    const int nblocks = 128 * GRID_H;   // one block per (b, h)
    ansi_kernel<<<nblocks, 320, 0, stream>>>(data, cm, out);
}

// Round 5
// 159.963 us; speedup vs baseline: 1.1339x; 1.0053x over previous
//
#include <hip/hip_runtime.h>

#define GRID_H 20
#define GRID_W 80
#define NCH 264
#define K 256
#define NPIX 128   // 16x8 glyph pixels

typedef __attribute__((ext_vector_type(8))) short short8;
typedef __attribute__((ext_vector_type(4))) float f32x4;
typedef __attribute__((ext_vector_type(8))) unsigned short u16x8;

static __device__ __forceinline__ unsigned short f2bf(float f) {
    unsigned int u = __builtin_bit_cast(unsigned int, f);
    u += 0x7FFFu + ((u >> 16) & 1u);   // round-to-nearest-even
    return (unsigned short)(u >> 16);
}

__global__ __launch_bounds__(320) void ansi_kernel(
        const float* __restrict__ data,
        const float* __restrict__ cm,
        float* __restrict__ out) {
    // 64 KB B tile, swizzled [p][c] — EXACT R1 layout; reused as output staging
    __shared__ alignas(16) unsigned short Bl[NPIX * K];
    __shared__ float fgbg[GRID_W * 8];   // per cell: bg.rgb, (fg-bg).rgb

    const int blk = blockIdx.x;
    const int b = blk / GRID_H;
    const int h = blk % GRID_H;
    const float* dbase = data + (size_t)(b * GRID_H + h) * GRID_W * NCH;
    const int t = threadIdx.x;

    // ---- stage char_matrix into LDS as bf16, transposed [p][c], XOR-swizzled ----
    for (int i = t; i < NPIX * (K / 8); i += 320) {
        int p  = i & (NPIX - 1);
        int cg = i >> 7;                 // channel group of 8 (0..31)
        const float* src = cm + (size_t)cg * 8 * NPIX + p;
        u16x8 pk;
        #pragma unroll
        for (int j = 0; j < 8; ++j) pk[j] = f2bf(src[j * NPIX]);
        int ba = (p * 512 + cg * 16) ^ ((p & 7) << 4);
        *reinterpret_cast<u16x8*>(reinterpret_cast<char*>(Bl) + ba) = pk;
    }

    // ---- stage per-cell fg/bg -> (bg, fg-bg) ----
    for (int w = t; w < GRID_W; w += 320) {
        const float* q = dbase + (size_t)w * NCH + 256;
        float4 a = *reinterpret_cast<const float4*>(q);      // fg_bold, fg.rgb
        float4 c = *reinterpret_cast<const float4*>(q + 4);  // bg_bold, bg.rgb
        float fs = 0.5f * a.x + 0.5f;
        float bs = 0.5f * c.x + 0.5f;
        float bgr = bs * c.y, bgg = bs * c.z, bgb = bs * c.w;
        float* o = &fgbg[w * 8];
        o[0] = bgr; o[1] = bgg; o[2] = bgb;
        o[3] = fs * a.y - bgr; o[4] = fs * a.z - bgg; o[5] = fs * a.w - bgb;
    }

    __syncthreads();

    // ---- main GEMM (EXACT R1): wave w -> cells [w*16, w*16+16), 128 pixels ----
    const int wave = t >> 6;
    const int lane = t & 63;
    const int mrow = lane & 15;     // A row / B col within tile
    const int g    = lane >> 4;     // k-group
    const int cell0 = wave * 16;

    const float* arow = dbase + (size_t)(cell0 + mrow) * NCH + g * 8;

    f32x4 acc[8];
    #pragma unroll
    for (int n = 0; n < 8; ++n) acc[n] = (f32x4){0.f, 0.f, 0.f, 0.f};

    for (int ks = 0; ks < 8; ++ks) {
        float4 a0 = *reinterpret_cast<const float4*>(arow + ks * 32);
        float4 a1 = *reinterpret_cast<const float4*>(arow + ks * 32 + 4);
        u16x8 ap;
        ap[0] = f2bf(a0.x); ap[1] = f2bf(a0.y); ap[2] = f2bf(a0.z); ap[3] = f2bf(a0.w);
        ap[4] = f2bf(a1.x); ap[5] = f2bf(a1.y); ap[6] = f2bf(a1.z); ap[7] = f2bf(a1.w);
        short8 afrag = __builtin_bit_cast(short8, ap);
        const int kbase = ks * 32 + g * 8;
        #pragma unroll
        for (int n = 0; n < 8; ++n) {
            int p = n * 16 + mrow;
            int ba = (p * 512 + kbase * 2) ^ ((p & 7) << 4);
            short8 bfrag = *reinterpret_cast<short8*>(reinterpret_cast<char*>(Bl) + ba);
            acc[n] = __builtin_amdgcn_mfma_f32_16x16x32_bf16(afrag, bfrag, acc[n], 0, 0, 0);
        }
    }

    __syncthreads();   // NEW: all waves done reading Bl before reuse as staging

    // ---- epilogue: out = bg + raw*(fg-bg), staged via LDS, coalesced stores ----
    const int col = lane & 15;
    const int rowbase = (lane >> 4) << 2;

    float bgv[4][3], dv[4][3];
    #pragma unroll
    for (int r = 0; r < 4; ++r) {
        const float* fb = &fgbg[(cell0 + rowbase + r) * 8];
        bgv[r][0] = fb[0]; bgv[r][1] = fb[1]; bgv[r][2] = fb[2];
        dv[r][0]  = fb[3]; dv[r][1]  = fb[4]; dv[r][2]  = fb[5];
    }

    float* S = (float*)Bl;   // 4 y-lines: 4*640*3 floats = 30720B < 64KB
    const size_t blockbase = ((size_t)b * 320 + h * 16) * 640 * 3;

    #pragma unroll
    for (int pass = 0; pass < 4; ++pass) {
        #pragma unroll
        for (int dn = 0; dn < 2; ++dn) {
            int n = pass * 2 + dn;              // static under unroll
            int pix = n * 16 + col;
            int yy = dn * 2 + (col >> 3);       // y-line within staging buffer
            int x = pix & 7;
            #pragma unroll
            for (int r = 0; r < 4; ++r) {
                int cell = cell0 + rowbase + r;
                float raw = acc[n][r];
                float* o = &S[(yy * 640 + cell * 8 + x) * 3];
                o[0] = bgv[r][0] + raw * dv[r][0];
                o[1] = bgv[r][1] + raw * dv[r][1];
                o[2] = bgv[r][2] + raw * dv[r][2];
            }
        }
        __syncthreads();
        // 7680 floats = 1920 float4 = 6 per thread, fully coalesced
        float4* od = (float4*)(out + blockbase + (size_t)pass * 7680);
        const float4* Sv = (const float4*)S;
        #pragma unroll
        for (int q = 0; q < 6; ++q) {
            int j = q * 320 + t;
            od[j] = Sv[j];
        }
        __syncthreads();   // before next pass overwrites S
    }
}

extern "C" void kernel_launch(void* const* d_in, const int* in_sizes, int n_in,
                              void* d_out, int out_size, void* d_ws, size_t ws_size,
                              hipStream_t stream) {
    (void)in_sizes; (void)n_in; (void)d_ws; (void)ws_size; (void)out_size;
    const float* data = (const float*)d_in[0];
    const float* cm   = (const float*)d_in[1];
    float* out        = (float*)d_out;
    const int nblocks = 128 * GRID_H;   // one block per (b, h)
    ansi_kernel<<<nblocks, 320, 0, stream>>>(data, cm, out);
}